// Round 3
// baseline (535.642 us; speedup 1.0000x reference)
//
#include <hip/hip_runtime.h>

#define NN 8192
#define HDIM 64
#define KDIM 128
#define LOG2E 1.44269504088896340736f
#define JT 128   // j-tile width
#define RB 32    // rows per block

// ---------------- Kernel 1: H = X@W (f32), per-row softmax constants ----------------
// grid 256 x 256 threads; 32 rows/block; 8 threads per row, 8 output cols each.
__global__ __launch_bounds__(256) void gat_prep(
    const float* __restrict__ X, const float* __restrict__ W,
    const float* __restrict__ al, const float* __restrict__ ar,
    float* __restrict__ Hf, float* __restrict__ el2p,
    float* __restrict__ cpv, float* __restrict__ erp)
{
    __shared__ float Wl[KDIM * HDIM]; // 32 KB
    const int t = threadIdx.x;
    {
        const float4* Wv = (const float4*)W;
        float4* Wlv = (float4*)Wl;
#pragma unroll
        for (int s = 0; s < 8; ++s) Wlv[t + s * 256] = Wv[t + s * 256];
    }
    __syncthreads();
    const int row = blockIdx.x * 32 + (t >> 3);
    const int cg = t & 7;
    const int c0 = cg * 8;
    float al8[8], ar8[8];
#pragma unroll
    for (int j = 0; j < 8; ++j) { al8[j] = al[c0 + j]; ar8[j] = ar[c0 + j]; }
    float acc[8];
#pragma unroll
    for (int j = 0; j < 8; ++j) acc[j] = 0.f;
    const float4* Xv = (const float4*)(X + row * KDIM);
    for (int k4 = 0; k4 < 32; ++k4) {
        float4 x4 = Xv[k4];
        float xs[4] = {x4.x, x4.y, x4.z, x4.w};
#pragma unroll
        for (int kk = 0; kk < 4; ++kk) {
            const int k = k4 * 4 + kk;
            const float x = xs[kk];
            const float4 w0 = *(const float4*)&Wl[k * HDIM + c0];
            const float4 w1 = *(const float4*)&Wl[k * HDIM + c0 + 4];
            acc[0] = fmaf(x, w0.x, acc[0]); acc[1] = fmaf(x, w0.y, acc[1]);
            acc[2] = fmaf(x, w0.z, acc[2]); acc[3] = fmaf(x, w0.w, acc[3]);
            acc[4] = fmaf(x, w1.x, acc[4]); acc[5] = fmaf(x, w1.y, acc[5]);
            acc[6] = fmaf(x, w1.z, acc[6]); acc[7] = fmaf(x, w1.w, acc[7]);
        }
    }
    float pl = 0.f, pr = 0.f;
#pragma unroll
    for (int j = 0; j < 8; ++j) {
        pl = fmaf(acc[j], al8[j], pl);
        pr = fmaf(acc[j], ar8[j], pr);
    }
    pl += __shfl_xor(pl, 1, 64); pl += __shfl_xor(pl, 2, 64); pl += __shfl_xor(pl, 4, 64);
    pr += __shfl_xor(pr, 1, 64); pr += __shfl_xor(pr, 2, 64); pr += __shfl_xor(pr, 4, 64);
    if (cg == 0) {
        const float el = pl;
        // m_i = leaky(e_l + 8) >= any row entry's pre-activation bound; softmax is
        // shift-invariant so ANY m works exactly; this choice avoids a pass over A.
        const float s8 = el + 8.0f;
        const float m = fmaxf(s8, 0.2f * s8);
        el2p[row] = (el - m) * LOG2E;
        cpv[row] = -0.8f * m * LOG2E;
        erp[row] = pr * LOG2E;
    }
#pragma unroll
    for (int j = 0; j < 8; ++j) Hf[row * HDIM + c0 + j] = acc[j];
}

// ---------------- Kernel 2: p = exp2((leaky(e)-m)*L) masked; out = (p@H)/rowsum ----
// grid 256 x 512 threads; 32 rows/block; j in 128-wide tiles; f32 LDS; 4x4 reg GEMM.
__global__ __launch_bounds__(512) void gat_main(
    const int* __restrict__ A, const float* __restrict__ Hf,
    const float* __restrict__ el2p, const float* __restrict__ cpv,
    const float* __restrict__ erp, float* __restrict__ out)
{
    __shared__ float pT[JT][36];  // [jj][row], padded
    __shared__ float Hs[JT][68];  // [jj][col], padded
    __shared__ float rowinv[RB];
    const int t = threadIdx.x;
    const int rowbase = blockIdx.x * RB;

    // p-phase assignment: 16 threads per row, 8 j's each
    const int pr = t >> 4;          // 0..31
    const int pj0 = (t & 15) * 8;   // 0..120
    const float el2 = el2p[rowbase + pr];
    const float cp = cpv[rowbase + pr];
    const int4* Ab = (const int4*)(A + (long)(rowbase + pr) * NN + pj0);
    float rs = 0.f;

    // GEMM assignment (t < 128): 4 rows x 4 cols per thread
    const int rq = t >> 4;  // 0..7 for t<128
    const int cq = t & 15;  // 0..15
    float acc[4][4];
#pragma unroll
    for (int r = 0; r < 4; ++r)
#pragma unroll
        for (int c = 0; c < 4; ++c) acc[r][c] = 0.f;

    for (int tile = 0; tile < NN / JT; ++tile) {
        const int jb = tile * JT;
        // stage Hs: 128 x 64 f32 = 2048 float4 by 512 threads
        const float4* Hv = (const float4*)(Hf + (long)jb * HDIM);
#pragma unroll
        for (int s = 0; s < 4; ++s) {
            const int f = t + s * 512;
            const int jj = f >> 4, c4 = f & 15;
            *(float4*)&Hs[jj][c4 * 4] = Hv[f];
        }
        // A + p for this thread's 8 j's
        const int4 a0 = Ab[tile * 32];
        const int4 a1 = Ab[tile * 32 + 1];
        const float4 e0 = *(const float4*)(erp + jb + pj0);
        const float4 e1 = *(const float4*)(erp + jb + pj0 + 4);
        const int am[8] = {a0.x, a0.y, a0.z, a0.w, a1.x, a1.y, a1.z, a1.w};
        const float ev[8] = {e0.x, e0.y, e0.z, e0.w, e1.x, e1.y, e1.z, e1.w};
#pragma unroll
        for (int c = 0; c < 8; ++c) {
            const float u = el2 + ev[c];
            const float v = fmaf(u, 0.2f, cp);
            float g = fmaxf(u, v);
            g = am[c] ? g : -1e30f;      // non-edge -> exp2 -> 0
            const float pp = exp2f(g);
            rs += pp;
            pT[pj0 + c][pr] = pp;
        }
        __syncthreads();
        if (t < 128) {
#pragma unroll 4
            for (int jj = 0; jj < JT; ++jj) {
                const float4 pv = *(const float4*)&pT[jj][rq * 4];
                const float4 hv = *(const float4*)&Hs[jj][cq * 4];
                const float pva[4] = {pv.x, pv.y, pv.z, pv.w};
                const float hva[4] = {hv.x, hv.y, hv.z, hv.w};
#pragma unroll
                for (int r = 0; r < 4; ++r)
#pragma unroll
                    for (int c = 0; c < 4; ++c)
                        acc[r][c] = fmaf(pva[r], hva[c], acc[r][c]);
            }
        }
        __syncthreads();
    }

    // denominator: 16 threads of row pr hold disjoint-j partials
    float v = rs;
    v += __shfl_xor(v, 1, 64); v += __shfl_xor(v, 2, 64);
    v += __shfl_xor(v, 4, 64); v += __shfl_xor(v, 8, 64);
    if ((t & 15) == 0) rowinv[pr] = 1.0f / v;
    __syncthreads();

    if (t < 128) {
#pragma unroll
        for (int r = 0; r < 4; ++r) {
            const int row = rq * 4 + r;
            const float ri = rowinv[row];
#pragma unroll
            for (int c = 0; c < 4; ++c)
                out[(long)(rowbase + row) * HDIM + cq * 4 + c] = acc[r][c] * ri;
        }
    }
}

extern "C" void kernel_launch(void* const* d_in, const int* in_sizes, int n_in,
                              void* d_out, int out_size, void* d_ws, size_t ws_size,
                              hipStream_t stream) {
    // resolve inputs by size (robust to ordering); dict order: X, A, W, a_l, a_r
    const float *X = nullptr, *W = nullptr, *al = nullptr, *ar = nullptr;
    const int* A = nullptr;
    for (int i = 0; i < n_in; ++i) {
        const long s = in_sizes[i];
        if (s == (long)NN * NN) A = (const int*)d_in[i];
        else if (s == (long)NN * KDIM) X = (const float*)d_in[i];
        else if (s == (long)KDIM * HDIM) W = (const float*)d_in[i];
        else if (s == HDIM) { if (!al) al = (const float*)d_in[i]; else ar = (const float*)d_in[i]; }
    }
    float* out = (float*)d_out;
    // workspace: Hf (8192*64 f32 = 2MB) + 3 x 8192 f32
    float* Hf = (float*)d_ws;
    float* el2p = Hf + (long)NN * HDIM;
    float* cpv = el2p + NN;
    float* erp = cpv + NN;
    hipLaunchKernelGGL(gat_prep, dim3(256), dim3(256), 0, stream, X, W, al, ar, Hf, el2p, cpv, erp);
    hipLaunchKernelGGL(gat_main, dim3(256), dim3(512), 0, stream, A, Hf, el2p, cpv, erp, out);
}

// Round 4
// 124.980 us; speedup vs baseline: 4.2858x; 4.2858x over previous
//
#include <hip/hip_runtime.h>

typedef __attribute__((ext_vector_type(8))) short short8v;
typedef __attribute__((ext_vector_type(4))) float f32x4;
typedef __attribute__((ext_vector_type(2))) unsigned int uint2v;

#define NN 8192
#define HDIM 64
#define KDIM 128
#define LOG2E 1.44269504088896340736f

__device__ __forceinline__ unsigned short f2b(float f) {
    unsigned int u = __float_as_uint(f);
    return (unsigned short)((u + 0x7fffu + ((u >> 16) & 1u)) >> 16);
}
__device__ __forceinline__ float b2f(unsigned short s) {
    return __uint_as_float(((unsigned int)s) << 16);
}

// ---------------- Kernel 1 (verified in R3): H = X@W, softmax row constants ----------
// Only change vs R3: store H as bf16 TRANSPOSED (HbT[c][row]) instead of f32 row-major.
__global__ __launch_bounds__(256) void gat_prep(
    const float* __restrict__ X, const float* __restrict__ W,
    const float* __restrict__ al, const float* __restrict__ ar,
    unsigned short* __restrict__ HbT, float* __restrict__ el2p,
    float* __restrict__ cpv, float* __restrict__ erp)
{
    __shared__ float Wl[KDIM * HDIM]; // 32 KB
    const int t = threadIdx.x;
    {
        const float4* Wv = (const float4*)W;
        float4* Wlv = (float4*)Wl;
#pragma unroll
        for (int s = 0; s < 8; ++s) Wlv[t + s * 256] = Wv[t + s * 256];
    }
    __syncthreads();
    const int row = blockIdx.x * 32 + (t >> 3);
    const int cg = t & 7;
    const int c0 = cg * 8;
    float al8[8], ar8[8];
#pragma unroll
    for (int j = 0; j < 8; ++j) { al8[j] = al[c0 + j]; ar8[j] = ar[c0 + j]; }
    float acc[8];
#pragma unroll
    for (int j = 0; j < 8; ++j) acc[j] = 0.f;
    const float4* Xv = (const float4*)(X + row * KDIM);
    for (int k4 = 0; k4 < 32; ++k4) {
        float4 x4 = Xv[k4];
        float xs[4] = {x4.x, x4.y, x4.z, x4.w};
#pragma unroll
        for (int kk = 0; kk < 4; ++kk) {
            const int k = k4 * 4 + kk;
            const float x = xs[kk];
            const float4 w0 = *(const float4*)&Wl[k * HDIM + c0];
            const float4 w1 = *(const float4*)&Wl[k * HDIM + c0 + 4];
            acc[0] = fmaf(x, w0.x, acc[0]); acc[1] = fmaf(x, w0.y, acc[1]);
            acc[2] = fmaf(x, w0.z, acc[2]); acc[3] = fmaf(x, w0.w, acc[3]);
            acc[4] = fmaf(x, w1.x, acc[4]); acc[5] = fmaf(x, w1.y, acc[5]);
            acc[6] = fmaf(x, w1.z, acc[6]); acc[7] = fmaf(x, w1.w, acc[7]);
        }
    }
    float pl = 0.f, pr = 0.f;
#pragma unroll
    for (int j = 0; j < 8; ++j) {
        pl = fmaf(acc[j], al8[j], pl);
        pr = fmaf(acc[j], ar8[j], pr);
    }
    pl += __shfl_xor(pl, 1, 64); pl += __shfl_xor(pl, 2, 64); pl += __shfl_xor(pl, 4, 64);
    pr += __shfl_xor(pr, 1, 64); pr += __shfl_xor(pr, 2, 64); pr += __shfl_xor(pr, 4, 64);
    if (cg == 0) {
        const float el = pl;
        // m_i = leaky(e_l + 8): upper bound of row entries; softmax is shift-invariant
        // so the shift is EXACT (verified in R3).
        const float s8 = el + 8.0f;
        const float m = fmaxf(s8, 0.2f * s8);
        el2p[row] = (el - m) * LOG2E;
        cpv[row] = -0.8f * m * LOG2E;
        erp[row] = pr * LOG2E;
    }
#pragma unroll
    for (int j = 0; j < 8; ++j) HbT[(c0 + j) * NN + row] = f2b(acc[j]);
}

// ---------------- Kernel 2: masked exp2 -> bf16 p in LDS -> MFMA p@H -> /rowsum -----
// grid 256 x 512; 32 rows/block; j in 256-wide tiles (32 tiles), 2-deep A prefetch.
// Wave w: phase1 rows {8i+w}; MFMA C-tile rows mh*16.. cols nq*16.. (mh=w>>2, nq=w&3).
__global__ __launch_bounds__(512) void gat_main(
    const int* __restrict__ A, const unsigned short* __restrict__ HbT,
    const float* __restrict__ el2p, const float* __restrict__ cpv,
    const float* __restrict__ erp, float* __restrict__ out)
{
    __shared__ unsigned short plds[2][32 * 264]; // bf16 p, row stride 264
    __shared__ float rowinv[32];
    const int t = threadIdx.x;
    const int l = t & 63;
    const int w = t >> 6;
    const int rowbase = blockIdx.x * 32;
    const int l15 = l & 15, lq = l >> 4;

    float el2c[4], cpc[4];
    const int4* Ap[4];
#pragma unroll
    for (int i = 0; i < 4; ++i) {
        const int gr = rowbase + 8 * i + w;
        el2c[i] = el2p[gr];
        cpc[i] = cpv[gr];
        Ap[i] = (const int4*)(A + (long)gr * NN + 4 * l);
    }
    float rsum[4] = {0.f, 0.f, 0.f, 0.f};
    f32x4 acc = {0.f, 0.f, 0.f, 0.f};
    const int mh = w >> 2, nq = w & 3;
    const unsigned short* bbase = HbT + (long)(nq * 16 + l15) * NN + lq * 8;
    const int aoff = (mh * 16 + l15) * 264 + lq * 8;

    int4 A0[4], A1[4];
    float4 E0, E1;

    auto loadT = [&](int4* av, float4& e4, int jt) {
        const int jb4 = jt * 64;
#pragma unroll
        for (int i = 0; i < 4; ++i) av[i] = Ap[i][jb4];
        e4 = *(const float4*)(erp + jt * 256 + 4 * l);
    };

    auto phase1 = [&](const int4* av, const float4 e4, unsigned short* buf) {
        const float e[4] = {e4.x, e4.y, e4.z, e4.w};
#pragma unroll
        for (int i = 0; i < 4; ++i) {
            const int am[4] = {av[i].x, av[i].y, av[i].z, av[i].w};
            unsigned short b[4];
#pragma unroll
            for (int c = 0; c < 4; ++c) {
                const float u = el2c[i] + e[c];
                const float v = fmaf(u, 0.2f, cpc[i]);
                float g = fmaxf(u, v);
                g = am[c] ? g : -1e30f; // non-edge -> exp2 -> 0
                const float pp = exp2f(g);
                b[c] = f2b(pp);
                rsum[i] += b2f(b[c]); // denominator from ROUNDED p (matches numerator)
            }
            const unsigned int lo = (unsigned int)b[0] | ((unsigned int)b[1] << 16);
            const unsigned int hi = (unsigned int)b[2] | ((unsigned int)b[3] << 16);
            *(uint2v*)(buf + (8 * i + w) * 264 + 4 * l) = (uint2v){lo, hi};
        }
    };

    auto mfmaT = [&](const unsigned short* buf, long jbase) {
        const unsigned short* bp = bbase + jbase;
#pragma unroll
        for (int kc = 0; kc < 8; ++kc) {
            short8v af = *(const short8v*)(buf + aoff + kc * 32);
            short8v bf = *(const short8v*)(bp + kc * 32);
            acc = __builtin_amdgcn_mfma_f32_16x16x32_bf16(af, bf, acc, 0, 0, 0);
        }
    };

    loadT(A0, E0, 0);
    loadT(A1, E1, 1);
    for (int jt = 0; jt < 32; jt += 2) {
        phase1(A0, E0, plds[0]);
        if (jt + 2 < 32) loadT(A0, E0, jt + 2); // prefetch 2 tiles ahead
        __syncthreads();
        mfmaT(plds[0], (long)jt * 256);
        phase1(A1, E1, plds[1]);
        if (jt + 3 < 32) loadT(A1, E1, jt + 3);
        __syncthreads();
        mfmaT(plds[1], (long)(jt + 1) * 256);
    }

    // rowsum: all 64 lanes hold disjoint-j partials of row 8i+w
#pragma unroll
    for (int i = 0; i < 4; ++i) {
        float v = rsum[i];
#pragma unroll
        for (int off = 32; off > 0; off >>= 1) v += __shfl_xor(v, off, 64);
        if (l == 0) rowinv[8 * i + w] = 1.0f / v;
    }
    __syncthreads();
#pragma unroll
    for (int r = 0; r < 4; ++r) {
        const int row = mh * 16 + lq * 4 + r; // D layout: col=lane&15, row=(lane>>4)*4+r
        const float o = acc[r] * rowinv[row];
        out[(long)(rowbase + row) * HDIM + nq * 16 + l15] = o;
    }
}

extern "C" void kernel_launch(void* const* d_in, const int* in_sizes, int n_in,
                              void* d_out, int out_size, void* d_ws, size_t ws_size,
                              hipStream_t stream) {
    // resolve inputs by size (robust to ordering); dict order: X, A, W, a_l, a_r
    const float *X = nullptr, *W = nullptr, *al = nullptr, *ar = nullptr;
    const int* A = nullptr;
    for (int i = 0; i < n_in; ++i) {
        const long s = in_sizes[i];
        if (s == (long)NN * NN) A = (const int*)d_in[i];
        else if (s == (long)NN * KDIM) X = (const float*)d_in[i];
        else if (s == (long)KDIM * HDIM) W = (const float*)d_in[i];
        else if (s == HDIM) { if (!al) al = (const float*)d_in[i]; else ar = (const float*)d_in[i]; }
    }
    float* out = (float*)d_out;
    // workspace: HbT (64*8192 bf16 = 1MB) + 3 x 8192 f32
    unsigned short* HbT = (unsigned short*)d_ws;
    float* el2p = (float*)((char*)d_ws + (long)NN * HDIM * 2);
    float* cpv = el2p + NN;
    float* erp = cpv + NN;
    hipLaunchKernelGGL(gat_prep, dim3(256), dim3(256), 0, stream, X, W, al, ar, HbT, el2p, cpv, erp);
    hipLaunchKernelGGL(gat_main, dim3(256), dim3(512), 0, stream, A, HbT, el2p, cpv, erp, out);
}